// Round 2
// baseline (734.234 us; speedup 1.0000x reference)
//
#include <hip/hip_runtime.h>
#include <hip/hip_bf16.h>
#include <stdint.h>

// Problem: out[b,p] = sum_g x[b,g] * (weight[p,g] * mask[g,p]) + bias[p]
// M=4096 (B), K=15000 (G), N=500 (P). fp32 in/out; bf16 MFMA inside.

#define M_DIM 4096
#define K_DIM 15000
#define N_DIM 500
#define KSTEPS 235            // ceil(15000/64)
#define K_PAD (KSTEPS * 64)   // 15040, zero-padded K tail
#define N_PAD 512             // zero-padded N

typedef __attribute__((ext_vector_type(4))) float f32x4;
typedef __attribute__((ext_vector_type(8))) short s16x8;   // 8 bf16 = 4 VGPRs (MFMA A/B frag)

static __device__ __forceinline__ uint32_t cvt_pk_bf16(float a, float b) {
  // packed RNE f32->bf16: low half = a, high half = b
  uint32_t r;
  asm("v_cvt_pk_bf16_f32 %0, %1, %2" : "=v"(r) : "v"(a), "v"(b));
  return r;
}

// ---------------------------------------------------------------------------
// Phase 1: W'[p][k] = weight[p][k] * mask[k][p]  -> bf16, padded [N_PAD][K_PAD]
// mask transposed through a padded LDS tile (both global accesses coalesced).
// ---------------------------------------------------------------------------
__global__ __launch_bounds__(256) void premult_kernel(
    const float* __restrict__ W, const float* __restrict__ Mk,
    __hip_bfloat16* __restrict__ Wp) {
  __shared__ float sm[64][65];   // 64 k x 64 p; pad 65 -> <=2-way banks on both phases
  const int g0 = blockIdx.x * 64;
  const int p0 = blockIdx.y * 64;
  const int t = threadIdx.x;
  const int l16 = t & 15;

  // load mask tile: rows g (coalesced along p). N_DIM%4==0 -> float4 all-or-nothing.
#pragma unroll
  for (int j = 0; j < 4; ++j) {
    int gl = (t >> 4) + 16 * j;
    int g = g0 + gl;
    int p = p0 + l16 * 4;
    f32x4 v = {0.f, 0.f, 0.f, 0.f};
    if (g < K_DIM && p < N_DIM)
      v = *(const f32x4*)(Mk + (size_t)g * N_DIM + p);
    // unconditional store: OOB rows/cols become 0 so downstream pads are clean
    sm[gl][l16 * 4 + 0] = v.x;
    sm[gl][l16 * 4 + 1] = v.y;
    sm[gl][l16 * 4 + 2] = v.z;
    sm[gl][l16 * 4 + 3] = v.w;
  }
  __syncthreads();

  const int pl = t >> 2;
  const int p = p0 + pl;
#pragma unroll
  for (int j = 0; j < 4; ++j) {
    int kq = (t & 3) + 4 * j;
    int k = kq * 4;
    int g = g0 + k;
    f32x4 w = {0.f, 0.f, 0.f, 0.f};
    if (p < N_DIM && g < K_DIM)   // K_DIM%4==0 -> float4 all-or-nothing
      w = *(const f32x4*)(W + (size_t)p * K_DIM + g);
    w.x *= sm[k + 0][pl];
    w.y *= sm[k + 1][pl];
    w.z *= sm[k + 2][pl];
    w.w *= sm[k + 3][pl];
    uint2 u;
    u.x = cvt_pk_bf16(w.x, w.y);
    u.y = cvt_pk_bf16(w.z, w.w);
    // always write (pads get zeros): ws is re-poisoned before every launch
    *(uint2*)((uint16_t*)Wp + (size_t)(p0 + pl) * K_PAD + g0 + k) = u;
  }
}

// ---------------------------------------------------------------------------
// Phase 2: C = X @ W'^T + bias.  BM=64, BN=128, BK=64, 4 waves (2x2),
// mfma_f32_16x16x32_bf16, double-buffered LDS, XOR-swizzled rows.
// Grid = 64 Mtiles * 4 Ntiles = 256 WGs (1/CU).
// ---------------------------------------------------------------------------
__global__ __launch_bounds__(256) void gemm_kernel(
    const float* __restrict__ X, const __hip_bfloat16* __restrict__ Wp,
    const float* __restrict__ bias, float* __restrict__ out) {
  __shared__ __hip_bfloat16 sA[2][64 * 64];    // 8KB each, row-major [m][k], swizzled
  __shared__ __hip_bfloat16 sB[2][128 * 64];   // 16KB each, row-major [n][k], swizzled

  // XCD-chunked swizzle: XCD c (bid%8==c) gets works c*32..c*32+31 ->
  // bm in [c*8, c*8+8) x all 4 bn: each 3.84MB x-slab is read by 4 WGs
  // co-resident on ONE XCD's 4MB L2.
  const int bid = blockIdx.x;
  const int work = (bid & 7) * 32 + (bid >> 3);
  const int bn = work & 3;
  const int bm = work >> 2;
  const int m0 = bm * 64, n0 = bn * 128;

  const int t = threadIdx.x;
  const int lane = t & 63;
  const int wid = t >> 6;
  const int wm = wid >> 1, wn = wid & 1;   // wave tile: rows wm*32.., cols wn*64..

  f32x4 acc[2][4] = {};

  f32x4 ar[4];    // staged A (fp32)
  uint4 brr[4];   // staged B (bf16 x8)

  auto loadA = [&](int g0k) {
#pragma unroll
    for (int j = 0; j < 4; ++j) {
      int m = (t >> 4) + 16 * j;
      int g = g0k + (t & 15) * 4;
      f32x4 z = {0.f, 0.f, 0.f, 0.f};
      ar[j] = (g < K_DIM) ? *(const f32x4*)(X + (size_t)(m0 + m) * K_DIM + g) : z;
    }
  };
  auto loadB = [&](int g0k) {
#pragma unroll
    for (int j = 0; j < 4; ++j) {
      int n = (t >> 3) + 32 * j;
      int slot = t & 7;
      brr[j] = *(const uint4*)((const uint16_t*)Wp + (size_t)(n0 + n) * K_PAD + g0k + slot * 8);
    }
  };
  auto writeA = [&](int buf) {
#pragma unroll
    for (int j = 0; j < 4; ++j) {
      int m = (t >> 4) + 16 * j;
      int off = (m * 128 + (t & 15) * 8) ^ ((m & 7) << 4);
      uint2 u;
      u.x = cvt_pk_bf16(ar[j].x, ar[j].y);
      u.y = cvt_pk_bf16(ar[j].z, ar[j].w);
      *(uint2*)((char*)sA[buf] + off) = u;
    }
  };
  auto writeB = [&](int buf) {
#pragma unroll
    for (int j = 0; j < 4; ++j) {
      int n = (t >> 3) + 32 * j;
      int slot = t & 7;
      int off = (n * 128 + slot * 16) ^ ((n & 7) << 4);
      *(uint4*)((char*)sB[buf] + off) = brr[j];
    }
  };
  auto compute = [&](int buf) {
#pragma unroll
    for (int ks = 0; ks < 2; ++ks) {
      const int kb2 = (ks * 32 + (lane >> 4) * 8) * 2;   // byte offset of k in row
      s16x8 a[2], b[4];
#pragma unroll
      for (int mf = 0; mf < 2; ++mf) {
        int row = wm * 32 + mf * 16 + (lane & 15);
        int off = (row * 128 + kb2) ^ ((row & 7) << 4);
        a[mf] = *(const s16x8*)((const char*)sA[buf] + off);
      }
#pragma unroll
      for (int nf = 0; nf < 4; ++nf) {
        int row = wn * 64 + nf * 16 + (lane & 15);
        int off = (row * 128 + kb2) ^ ((row & 7) << 4);
        b[nf] = *(const s16x8*)((const char*)sB[buf] + off);
      }
#pragma unroll
      for (int mf = 0; mf < 2; ++mf)
#pragma unroll
        for (int nf = 0; nf < 4; ++nf)
          acc[mf][nf] = __builtin_amdgcn_mfma_f32_16x16x32_bf16(a[mf], b[nf], acc[mf][nf], 0, 0, 0);
    }
  };

  // prologue
  loadA(0);
  loadB(0);
  writeA(0);
  writeB(0);
  __syncthreads();

  int cur = 0;
  for (int tt = 0; tt < KSTEPS; ++tt) {
    const bool more = (tt + 1 < KSTEPS);
    if (more) { loadA((tt + 1) * 64); loadB((tt + 1) * 64); }  // overlap with compute
    compute(cur);
    if (more) { writeA(cur ^ 1); writeB(cur ^ 1); }
    __syncthreads();
    cur ^= 1;
  }

  // epilogue: C/D layout (verified m89): col = lane&15, row = (lane>>4)*4 + r
#pragma unroll
  for (int mf = 0; mf < 2; ++mf) {
    int row0 = m0 + wm * 32 + mf * 16 + (lane >> 4) * 4;
#pragma unroll
    for (int nf = 0; nf < 4; ++nf) {
      int col = n0 + wn * 64 + nf * 16 + (lane & 15);
      if (col < N_DIM) {
        float bv = bias[col];
#pragma unroll
        for (int r = 0; r < 4; ++r)
          out[(size_t)(row0 + r) * N_DIM + col] = acc[mf][nf][r] + bv;
      }
    }
  }
}

// ---------------------------------------------------------------------------
// Fallback (only if ws too small for W'): slow but exact fp32.
// ---------------------------------------------------------------------------
__global__ void naive_kernel(const float* __restrict__ X, const float* __restrict__ W,
                             const float* __restrict__ Mk, const float* __restrict__ bias,
                             float* __restrict__ out) {
  size_t idx = (size_t)blockIdx.x * 256 + threadIdx.x;
  if (idx >= (size_t)M_DIM * N_DIM) return;
  int b = (int)(idx / N_DIM), p = (int)(idx % N_DIM);
  const float* xr = X + (size_t)b * K_DIM;
  const float* wr = W + (size_t)p * K_DIM;
  float acc = 0.f;
  for (int g = 0; g < K_DIM; ++g)
    acc = fmaf(xr[g] * wr[g], Mk[(size_t)g * N_DIM + p], acc);
  out[idx] = acc + bias[p];
}

extern "C" void kernel_launch(void* const* d_in, const int* in_sizes, int n_in,
                              void* d_out, int out_size, void* d_ws, size_t ws_size,
                              hipStream_t stream) {
  const float* x = (const float*)d_in[0];
  const float* w = (const float*)d_in[1];
  const float* mk = (const float*)d_in[2];
  const float* bias = (const float*)d_in[3];
  float* out = (float*)d_out;

  const size_t need = (size_t)N_PAD * K_PAD * sizeof(__hip_bfloat16);  // ~14.7MB
  if (ws_size >= need) {
    __hip_bfloat16* wp = (__hip_bfloat16*)d_ws;
    premult_kernel<<<dim3(KSTEPS, N_PAD / 64), 256, 0, stream>>>(w, mk, wp);
    gemm_kernel<<<256, 256, 0, stream>>>(x, wp, bias, out);
  } else {
    naive_kernel<<<((size_t)M_DIM * N_DIM + 255) / 256, 256, 0, stream>>>(x, w, mk, bias, out);
  }
}

// Round 7
// 538.225 us; speedup vs baseline: 1.3642x; 1.3642x over previous
//
#include <hip/hip_runtime.h>
#include <hip/hip_bf16.h>
#include <stdint.h>

// out[b,p] = sum_g x[b,g] * (weight[p,g] * mask[g,p]) + bias[p]
// M=4096 (B), K=15000 (G), N=500 (P). fp32 in/out; bf16 MFMA inside.

#define M_DIM 4096
#define K_DIM 15000
#define N_DIM 500
#define N_PAD 512
#define PRE_KSTEPS 235
#define K_PAD (PRE_KSTEPS * 64)   // 15040: Wp zero-padded K

// GEMM geometry: BM=128, BN=128, BK=32, split-K x4 -> 32*4*4 = 512 WGs (2/CU)
#define BM 128
#define BN 128
#define BK 32
#define TOT_STEPS 469             // 468 full 32-steps + 1 tail (24 elems)

typedef __attribute__((ext_vector_type(4))) float f32x4;
typedef __attribute__((ext_vector_type(8))) short s16x8;

static __device__ __forceinline__ uint32_t cvt_pk_bf16(float a, float b) {
  uint32_t r;
  asm("v_cvt_pk_bf16_f32 %0, %1, %2" : "=v"(r) : "v"(a), "v"(b));
  return r;
}

// async global->LDS, 16B per lane. lds dest must be wave-uniform base (+lane*16 by HW).
static __device__ __forceinline__ void async16(const void* g, void* l) {
  __builtin_amdgcn_global_load_lds(
      (const __attribute__((address_space(1))) uint32_t*)g,
      (__attribute__((address_space(3))) uint32_t*)l, 16, 0, 0);
}

// ---------------------------------------------------------------------------
// out[b][p] = bias[p]  (atomics accumulate on top)
// ---------------------------------------------------------------------------
__global__ __launch_bounds__(256) void init_out(const float* __restrict__ bias,
                                                float* __restrict__ out) {
  int i = blockIdx.x * 256 + threadIdx.x;          // over float4s
  if (i < M_DIM * N_DIM / 4) {
    int p = (i * 4) % N_DIM;                       // N_DIM%4==0 -> row-aligned
    *(f32x4*)(out + (size_t)i * 4) = *(const f32x4*)(bias + p);
  }
}

// ---------------------------------------------------------------------------
// W'[p][k] = weight[p][k] * mask[k][p] -> bf16, padded [N_PAD][K_PAD] (zeros)
// ---------------------------------------------------------------------------
__global__ __launch_bounds__(256) void premult_kernel(
    const float* __restrict__ W, const float* __restrict__ Mk,
    __hip_bfloat16* __restrict__ Wp) {
  __shared__ float sm[64][65];
  const int g0 = blockIdx.x * 64;
  const int p0 = blockIdx.y * 64;
  const int t = threadIdx.x;
  const int l16 = t & 15;

#pragma unroll
  for (int j = 0; j < 4; ++j) {
    int gl = (t >> 4) + 16 * j;
    int g = g0 + gl;
    int p = p0 + l16 * 4;
    f32x4 v = {0.f, 0.f, 0.f, 0.f};
    if (g < K_DIM && p < N_DIM)
      v = *(const f32x4*)(Mk + (size_t)g * N_DIM + p);
    sm[gl][l16 * 4 + 0] = v.x;
    sm[gl][l16 * 4 + 1] = v.y;
    sm[gl][l16 * 4 + 2] = v.z;
    sm[gl][l16 * 4 + 3] = v.w;
  }
  __syncthreads();

  const int pl = t >> 2;
  const int p = p0 + pl;
#pragma unroll
  for (int j = 0; j < 4; ++j) {
    int k = ((t & 3) + 4 * j) * 4;
    int g = g0 + k;
    f32x4 w = {0.f, 0.f, 0.f, 0.f};
    if (p < N_DIM && g < K_DIM)
      w = *(const f32x4*)(W + (size_t)p * K_DIM + g);
    w.x *= sm[k + 0][pl];
    w.y *= sm[k + 1][pl];
    w.z *= sm[k + 2][pl];
    w.w *= sm[k + 3][pl];
    uint2 u;
    u.x = cvt_pk_bf16(w.x, w.y);
    u.y = cvt_pk_bf16(w.z, w.w);
    *(uint2*)((uint16_t*)Wp + (size_t)(p0 + pl) * K_PAD + g0 + k) = u;
  }
}

// ---------------------------------------------------------------------------
// Split-K GEMM: partial C(128x128) over ~117 K-steps, atomicAdd into out.
// A: fp32 in LDS via global_load_lds (pre-swizzled src), cvt->bf16 on read.
// B: bf16 in LDS via global_load_lds (pre-swizzled src).
// 8 waves (2x4), wave tile 64x32, mfma_f32_16x16x32_bf16.
// ---------------------------------------------------------------------------
__global__ __launch_bounds__(512, 4) void gemm_splitk(
    const float* __restrict__ X, const __hip_bfloat16* __restrict__ Wp,
    float* __restrict__ out) {
  __shared__ float sA[2][BM * BK];            // 16KB/buf, rows 128B, swz ^(r&7)<<4
  __shared__ __hip_bfloat16 sB[2][BN * BK];   // 8KB/buf,  rows 64B,  swz ^(r&3)<<4

  // XCD-chunked: XCD x gets works [x*64,(x+1)*64) = 4 bm-slabs complete
  // (all ks,bn of a bm co-resident -> X window 1 HBM fetch, L2 reuse x4 bn).
  const int bid = blockIdx.x;
  const int work = (bid & 7) * 64 + (bid >> 3);
  const int bm = work >> 4;        // 0..31
  const int ks = (work >> 2) & 3;  // 0..3
  const int bn = work & 3;         // 0..3
  const int m0 = bm * BM;
  const int n0 = bn * BN;

  // K ranges over TOT_STEPS=469: ks0 gets 118, ks1..3 get 117. Tail step 468 in ks3.
  const int kstart = ks * 117 + (ks > 0 ? 1 : 0);
  const int kcount = 117 + (ks == 0 ? 1 : 0);

  const int t = threadIdx.x;
  const int lane = t & 63;
  const int w = t >> 6;
  const int wrow = w >> 2;   // 0..1 -> rows wrow*64
  const int wcol = w & 3;    // 0..3 -> cols wcol*32
  const int l15 = lane & 15;
  const int q = lane >> 4;   // 0..3

  // --- staging addressing (loop-invariant except +kk) ---
  // A instr i: dest d = i*8192 + t*16; row = i*64 + (t>>3); swizzled src col
  const int arow = t >> 3;
  const int acol = ((t & 7) ^ ((t >> 3) & 7)) * 4;   // element offset in row
  const float* gA0 = X + (size_t)(m0 + arow) * K_DIM + acol;
  const float* gA1 = X + (size_t)(m0 + 64 + arow) * K_DIM + acol;
  // B: dest d = t*16; row = t>>2; swizzled src col
  const int bcol = ((t & 3) ^ ((t >> 2) & 3)) * 8;
  const __hip_bfloat16* gB = Wp + (size_t)(n0 + (t >> 2)) * K_PAD + bcol;

  // wave-uniform LDS byte bases
  const int ldsA0 = w * 1024;
  const int ldsA1 = 8192 + w * 1024;
  const int ldsB = w * 1024;

  f32x4 acc[4][2] = {};

  auto stage = [&](int buf, int st) {
    const int kk = st * BK;
    if (kk + BK <= K_DIM) {
      async16(gA0 + kk, (char*)sA[buf] + ldsA0);
      async16(gA1 + kk, (char*)sA[buf] + ldsA1);
      async16(gB + kk, (char*)sB[buf] + ldsB);
    } else {
      // tail step (24 real elems): B is zero-padded in Wp -> async fine;
      // A reg-staged with zero guard (wave-uniform branch, runs once for ks==3).
      async16(gB + kk, (char*)sB[buf] + ldsB);
      f32x4 z = {0.f, 0.f, 0.f, 0.f};
      bool ok = (kk + acol + 4 <= K_DIM);
      f32x4 v0 = ok ? *(const f32x4*)(gA0 + kk) : z;
      f32x4 v1 = ok ? *(const f32x4*)(gA1 + kk) : z;
      *(f32x4*)((char*)sA[buf] + ldsA0 + lane * 16) = v0;
      *(f32x4*)((char*)sA[buf] + ldsA1 + lane * 16) = v1;
    }
  };

  auto compute = [&](int buf) {
    const char* pA = (const char*)sA[buf];
    const char* pB = (const char*)sB[buf];
    s16x8 av[4], bv[2];
#pragma unroll
    for (int mf = 0; mf < 4; ++mf) {
      int r = wrow * 64 + mf * 16 + l15;
      int off = (r * 128 + q * 32) ^ ((r & 7) << 4);
      f32x4 a0 = *(const f32x4*)(pA + off);
      f32x4 a1 = *(const f32x4*)(pA + (off ^ 16));
      union { uint4 u; s16x8 v; } c;
      c.u.x = cvt_pk_bf16(a0.x, a0.y);
      c.u.y = cvt_pk_bf16(a0.z, a0.w);
      c.u.z = cvt_pk_bf16(a1.x, a1.y);
      c.u.w = cvt_pk_bf16(a1.z, a1.w);
      av[mf] = c.v;
    }
#pragma unroll
    for (int nf = 0; nf < 2; ++nf) {
      int r = wcol * 32 + nf * 16 + l15;
      int off = (r * 64 + q * 16) ^ ((r & 3) << 4);
      bv[nf] = *(const s16x8*)(pB + off);
    }
#pragma unroll
    for (int mf = 0; mf < 4; ++mf)
#pragma unroll
      for (int nf = 0; nf < 2; ++nf)
        acc[mf][nf] = __builtin_amdgcn_mfma_f32_16x16x32_bf16(av[mf], bv[nf], acc[mf][nf], 0, 0, 0);
  };

  int cur = 0;
  stage(0, kstart);
  for (int it = 0; it < kcount; ++it) {
    __syncthreads();                             // vmcnt drain -> buf[cur] ready
    if (it + 1 < kcount) stage(cur ^ 1, kstart + it + 1);
    compute(cur);
    cur ^= 1;
  }

  // epilogue: C/D layout col = lane&15, row = (lane>>4)*4 + r (verified m89)
#pragma unroll
  for (int mf = 0; mf < 4; ++mf) {
    int row0 = m0 + wrow * 64 + mf * 16 + q * 4;
#pragma unroll
    for (int nf = 0; nf < 2; ++nf) {
      int col = n0 + wcol * 32 + nf * 16 + l15;
      if (col < N_DIM) {
#pragma unroll
        for (int r = 0; r < 4; ++r)
          atomicAdd(out + (size_t)(row0 + r) * N_DIM + col, acc[mf][nf][r]);
      }
    }
  }
}

// ---------------------------------------------------------------------------
// Fallback (ws too small): slow but exact fp32.
// ---------------------------------------------------------------------------
__global__ void naive_kernel(const float* __restrict__ X, const float* __restrict__ W,
                             const float* __restrict__ Mk, const float* __restrict__ bias,
                             float* __restrict__ out) {
  size_t idx = (size_t)blockIdx.x * 256 + threadIdx.x;
  if (idx >= (size_t)M_DIM * N_DIM) return;
  int b = (int)(idx / N_DIM), p = (int)(idx % N_DIM);
  const float* xr = X + (size_t)b * K_DIM;
  const float* wr = W + (size_t)p * K_DIM;
  float acc = 0.f;
  for (int g = 0; g < K_DIM; ++g)
    acc = fmaf(xr[g] * wr[g], Mk[(size_t)g * N_DIM + p], acc);
  out[idx] = acc + bias[p];
}

extern "C" void kernel_launch(void* const* d_in, const int* in_sizes, int n_in,
                              void* d_out, int out_size, void* d_ws, size_t ws_size,
                              hipStream_t stream) {
  const float* x = (const float*)d_in[0];
  const float* w = (const float*)d_in[1];
  const float* mk = (const float*)d_in[2];
  const float* bias = (const float*)d_in[3];
  float* out = (float*)d_out;

  const size_t need = (size_t)N_PAD * K_PAD * sizeof(__hip_bfloat16);  // ~14.7MB
  if (ws_size >= need) {
    __hip_bfloat16* wp = (__hip_bfloat16*)d_ws;
    init_out<<<M_DIM * N_DIM / 4 / 256, 256, 0, stream>>>(bias, out);
    premult_kernel<<<dim3(PRE_KSTEPS, N_PAD / 64), 256, 0, stream>>>(w, mk, wp);
    gemm_splitk<<<512, 512, 0, stream>>>(x, wp, out);
  } else {
    naive_kernel<<<((size_t)M_DIM * N_DIM + 255) / 256, 256, 0, stream>>>(x, w, mk, bias, out);
  }
}

// Round 8
// 530.223 us; speedup vs baseline: 1.3848x; 1.0151x over previous
//
#include <hip/hip_runtime.h>
#include <hip/hip_bf16.h>
#include <stdint.h>

// out[b,p] = sum_g x[b,g] * (weight[p,g] * mask[g,p]) + bias[p]
// M=4096 (B), K=15000 (G), N=500 (P). fp32 in/out; bf16 MFMA inside.

#define M_DIM 4096
#define K_DIM 15000
#define N_DIM 500
#define N_PAD 512
#define PRE_KSTEPS 235
#define K_PAD (PRE_KSTEPS * 64)   // 15040: Wp zero-padded K

// GEMM: BM=BN=128, BK=32, 4 waves (2x2) of 64x64 tiles, split-K x6
// grid = 32 bm * 4 bn * 6 ks = 768 WGs; LDS 48KB -> 3 WG/CU (12 waves/CU)
#define BK 32
#define KS_SPLIT 6
#define STEPS_PER 78              // 78*6 = 468 full steps; ks5 takes the +1 tail

typedef __attribute__((ext_vector_type(4))) float f32x4;
typedef __attribute__((ext_vector_type(8))) short s16x8;

static __device__ __forceinline__ uint32_t cvt_pk_bf16(float a, float b) {
  uint32_t r;
  asm("v_cvt_pk_bf16_f32 %0, %1, %2" : "=v"(r) : "v"(a), "v"(b));
  return r;
}

// async global->LDS, 16B/lane. lds dest = wave-uniform base (+lane*16 by HW).
static __device__ __forceinline__ void async16(const void* g, void* l) {
  __builtin_amdgcn_global_load_lds(
      (const __attribute__((address_space(1))) uint32_t*)g,
      (__attribute__((address_space(3))) uint32_t*)l, 16, 0, 0);
}

// ---------------------------------------------------------------------------
// out[b][p] = bias[p]  (atomics accumulate on top)
// ---------------------------------------------------------------------------
__global__ __launch_bounds__(256) void init_out(const float* __restrict__ bias,
                                                float* __restrict__ out) {
  int i = blockIdx.x * 256 + threadIdx.x;          // over float4s
  if (i < M_DIM * N_DIM / 4) {
    int p = (i * 4) % N_DIM;                       // N_DIM%4==0 -> row-aligned
    *(f32x4*)(out + (size_t)i * 4) = *(const f32x4*)(bias + p);
  }
}

// ---------------------------------------------------------------------------
// W'[p][k] = weight[p][k] * mask[k][p] -> bf16, padded [N_PAD][K_PAD] (zeros)
// ---------------------------------------------------------------------------
__global__ __launch_bounds__(256) void premult_kernel(
    const float* __restrict__ W, const float* __restrict__ Mk,
    __hip_bfloat16* __restrict__ Wp) {
  __shared__ float sm[64][65];
  const int g0 = blockIdx.x * 64;
  const int p0 = blockIdx.y * 64;
  const int t = threadIdx.x;
  const int l16 = t & 15;

#pragma unroll
  for (int j = 0; j < 4; ++j) {
    int gl = (t >> 4) + 16 * j;
    int g = g0 + gl;
    int p = p0 + l16 * 4;
    f32x4 v = {0.f, 0.f, 0.f, 0.f};
    if (g < K_DIM && p < N_DIM)
      v = *(const f32x4*)(Mk + (size_t)g * N_DIM + p);
    sm[gl][l16 * 4 + 0] = v.x;
    sm[gl][l16 * 4 + 1] = v.y;
    sm[gl][l16 * 4 + 2] = v.z;
    sm[gl][l16 * 4 + 3] = v.w;
  }
  __syncthreads();

  const int pl = t >> 2;
  const int p = p0 + pl;
#pragma unroll
  for (int j = 0; j < 4; ++j) {
    int k = ((t & 3) + 4 * j) * 4;
    int g = g0 + k;
    f32x4 w = {0.f, 0.f, 0.f, 0.f};
    if (p < N_DIM && g < K_DIM)
      w = *(const f32x4*)(W + (size_t)p * K_DIM + g);
    w.x *= sm[k + 0][pl];
    w.y *= sm[k + 1][pl];
    w.z *= sm[k + 2][pl];
    w.w *= sm[k + 3][pl];
    uint2 u;
    u.x = cvt_pk_bf16(w.x, w.y);
    u.y = cvt_pk_bf16(w.z, w.w);
    *(uint2*)((uint16_t*)Wp + (size_t)(p0 + pl) * K_PAD + g0 + k) = u;
  }
}

// ---------------------------------------------------------------------------
// Split-K GEMM. A: f32 in LDS (global_load_lds, pre-swizzled src, cvt on
// read). B: bf16 in LDS (global_load_lds, pre-swizzled src). 4 waves of
// 64x64 tiles (4x4 x mfma_f32_16x16x32_bf16), 2-phase double-buffer loop.
// ---------------------------------------------------------------------------
__global__ __launch_bounds__(256, 3) void gemm_splitk(
    const float* __restrict__ X, const __hip_bfloat16* __restrict__ Wp,
    float* __restrict__ out) {
  __shared__ float sA[2][128 * BK];            // 16KB/buf, rows 128B; slot s of row r holds chunk s^(r&7)
  __shared__ __hip_bfloat16 sB[2][128 * BK];   // 8KB/buf, rows 64B; slot c of row r holds chunk c^((r>>1)&3)

  // XCD-chunked: 96 WGs per XCD (exactly resident at 3 WG/CU x 32 CU):
  // 4 bm-slabs x 6 ks x 4 bn, bn fastest -> A-tile sharers are L2 neighbors.
  const int bid = blockIdx.x;
  const int xcd = bid & 7;
  const int ii = bid >> 3;           // 0..95
  const int bm = xcd * 4 + ii / 24;  // 0..31
  const int rem = ii % 24;
  const int ks = rem >> 2;           // 0..5
  const int bn = rem & 3;            // 0..3
  const int m0 = bm * 128, n0 = bn * 128;

  const int kstart = ks * STEPS_PER;
  const int kcount = STEPS_PER + (ks == KS_SPLIT - 1 ? 1 : 0);  // 469 total

  const int t = threadIdx.x;
  const int lane = t & 63;
  const int w = t >> 6;              // 0..3
  const int wm = w >> 1, wn = w & 1; // wave tile: rows wm*64.., cols wn*64..
  const int l15 = lane & 15;
  const int q = lane >> 4;           // 0..3

  // --- staging addressing ---
  // A: instr j stages rows [32j,32j+32) -> lds j*4096 + t*16.
  //    linear slot (t&7) must hold global chunk (t&7)^(row&7), row&7=(t>>3)&7.
  const int achunk = (t & 7) ^ ((t >> 3) & 7);
  const float* gA = X + (size_t)(m0 + (t >> 3)) * K_DIM + achunk * 4;
  // B: instr j stages rows [64j,64j+64) -> lds j*4096 + t*16.
  //    linear slot (t&3) holds global chunk (t&3)^((row>>1)&3), row=t>>2.
  const int bchunk = (t & 3) ^ ((t >> 3) & 3);
  const __hip_bfloat16* gB = Wp + (size_t)(n0 + (t >> 2)) * K_PAD + bchunk * 8;

  f32x4 acc[4][4] = {};

  auto stage = [&](int buf, int st) {
    const int kk = st * BK;
    if (kk + BK <= K_DIM) {
#pragma unroll
      for (int j = 0; j < 4; ++j)
        async16(gA + kk + (size_t)(32 * j) * K_DIM,
                (char*)sA[buf] + j * 4096 + w * 1024);
#pragma unroll
      for (int j = 0; j < 2; ++j)
        async16(gB + kk + (size_t)(64 * j) * K_PAD,
                (char*)sB[buf] + j * 4096 + w * 1024);
    } else {
      // tail step (24 real k): B zero-padded in Wp -> async fine;
      // A reg-staged with per-lane zero guard (avoids OOB read past X end).
#pragma unroll
      for (int j = 0; j < 2; ++j)
        async16(gB + kk + (size_t)(64 * j) * K_PAD,
                (char*)sB[buf] + j * 4096 + w * 1024);
      const bool ok = (kk + achunk * 4 + 4 <= K_DIM);
#pragma unroll
      for (int j = 0; j < 4; ++j) {
        f32x4 z = {0.f, 0.f, 0.f, 0.f};
        f32x4 v = ok ? *(const f32x4*)(gA + kk + (size_t)(32 * j) * K_DIM) : z;
        *(f32x4*)((char*)sA[buf] + j * 4096 + t * 16) = v;
      }
    }
  };

  auto compute = [&](int buf) {
    const char* pA = (const char*)sA[buf];
    const char* pB = (const char*)sB[buf];
    s16x8 av[4], bv[4];
#pragma unroll
    for (int mf = 0; mf < 4; ++mf) {
      int r = wm * 64 + mf * 16 + l15;
      int base = r * 128 + (((2 * q) ^ (r & 7)) << 4);   // chunk 2q
      f32x4 a0 = *(const f32x4*)(pA + base);
      f32x4 a1 = *(const f32x4*)(pA + (base ^ 16));      // chunk 2q+1
      union { uint4 u; s16x8 v; } c;
      c.u.x = cvt_pk_bf16(a0.x, a0.y);
      c.u.y = cvt_pk_bf16(a0.z, a0.w);
      c.u.z = cvt_pk_bf16(a1.x, a1.y);
      c.u.w = cvt_pk_bf16(a1.z, a1.w);
      av[mf] = c.v;
    }
#pragma unroll
    for (int nf = 0; nf < 4; ++nf) {
      int r = wn * 64 + nf * 16 + l15;
      int base = r * 64 + ((q ^ ((r >> 1) & 3)) << 4);   // chunk q
      bv[nf] = *(const s16x8*)(pB + base);
    }
#pragma unroll
    for (int mf = 0; mf < 4; ++mf)
#pragma unroll
      for (int nf = 0; nf < 4; ++nf)
        acc[mf][nf] = __builtin_amdgcn_mfma_f32_16x16x32_bf16(av[mf], bv[nf], acc[mf][nf], 0, 0, 0);
  };

  int cur = 0;
  stage(0, kstart);
  for (int it = 0; it < kcount; ++it) {
    __syncthreads();                           // vmcnt drain -> buf[cur] ready
    if (it + 1 < kcount) stage(cur ^ 1, kstart + it + 1);
    compute(cur);
    cur ^= 1;
  }

  // epilogue: C/D layout col = lane&15, row = (lane>>4)*4 + r (verified m89)
#pragma unroll
  for (int mf = 0; mf < 4; ++mf) {
    int row0 = m0 + wm * 64 + mf * 16 + q * 4;
#pragma unroll
    for (int nf = 0; nf < 4; ++nf) {
      int col = n0 + wn * 64 + nf * 16 + l15;
      if (col < N_DIM) {
#pragma unroll
        for (int r = 0; r < 4; ++r)
          atomicAdd(out + (size_t)(row0 + r) * N_DIM + col, acc[mf][nf][r]);
      }
    }
  }
}

// ---------------------------------------------------------------------------
// Fallback (ws too small): slow but exact fp32.
// ---------------------------------------------------------------------------
__global__ void naive_kernel(const float* __restrict__ X, const float* __restrict__ W,
                             const float* __restrict__ Mk, const float* __restrict__ bias,
                             float* __restrict__ out) {
  size_t idx = (size_t)blockIdx.x * 256 + threadIdx.x;
  if (idx >= (size_t)M_DIM * N_DIM) return;
  int b = (int)(idx / N_DIM), p = (int)(idx % N_DIM);
  const float* xr = X + (size_t)b * K_DIM;
  const float* wr = W + (size_t)p * K_DIM;
  float acc = 0.f;
  for (int g = 0; g < K_DIM; ++g)
    acc = fmaf(xr[g] * wr[g], Mk[(size_t)g * N_DIM + p], acc);
  out[idx] = acc + bias[p];
}

extern "C" void kernel_launch(void* const* d_in, const int* in_sizes, int n_in,
                              void* d_out, int out_size, void* d_ws, size_t ws_size,
                              hipStream_t stream) {
  const float* x = (const float*)d_in[0];
  const float* w = (const float*)d_in[1];
  const float* mk = (const float*)d_in[2];
  const float* bias = (const float*)d_in[3];
  float* out = (float*)d_out;

  const size_t need = (size_t)N_PAD * K_PAD * sizeof(__hip_bfloat16);  // ~14.7MB
  if (ws_size >= need) {
    __hip_bfloat16* wp = (__hip_bfloat16*)d_ws;
    init_out<<<M_DIM * N_DIM / 4 / 256, 256, 0, stream>>>(bias, out);
    premult_kernel<<<dim3(PRE_KSTEPS, N_PAD / 64), 256, 0, stream>>>(w, mk, wp);
    gemm_splitk<<<768, 256, 0, stream>>>(x, wp, out);
  } else {
    naive_kernel<<<((size_t)M_DIM * N_DIM + 255) / 256, 256, 0, stream>>>(x, w, mk, bias, out);
  }
}